// Round 5
// baseline (60.452 us; speedup 1.0000x reference)
//
#include <hip/hip_runtime.h>
#include <utility>

#define DEV __device__ __forceinline__

constexpr int NV = 16;
constexpr float STEP = 0.1f;
constexpr int MAX_ITER = 20;
constexpr int LDA = 20;  // padded LDS row stride: 80 B -> 2-way bank alias only (free)

// ---- compile-time for loop (DPP ctrl / register indices must be ICEs) ----
template <class F, int... Is>
DEV void sf_impl(F&& f, std::integer_sequence<int, Is...>) {
  (f(std::integral_constant<int, Is>{}), ...);
}
template <int N, class F>
DEV void static_for(F&& f) {
  sf_impl(f, std::make_integer_sequence<int, N>{});
}

// ---- broadcast lane Q within each quad via DPP quad_perm (pure VALU, no LDS) ----
template <int Q>
DEV float qbcast(float v) {
  int iv = __float_as_int(v);
  int r = __builtin_amdgcn_update_dpp(iv, iv, Q * 0x55, 0xF, 0xF, true);
  return __int_as_float(r);
}

DEV float rcp_fast(float x) { return __builtin_amdgcn_rcpf(x); }

// One quad per system; lane l owns rows {4l..4l+3}. u-substitution:
// solve (A + diag(3y^2/cos)) u = b, delta = u/cos. A staged in LDS.
// R5 change: one-step software pipeline of the Gauss-Jordan spine --
// per step: finalize col k+1 FIRST, start rcp for step k+1, slip b-update
// and col k+2 into the rcp shadow, compute f_next/bk_next mid-burst, then
// sweep cols k+3..15. Serial links overlap fma bursts instead of heading them.
__global__ __attribute__((amdgpu_flat_work_group_size(256, 256),
                          amdgpu_waves_per_eu(2, 2)))
void newton16(const float* __restrict__ y0, const float* __restrict__ xin,
              const float* __restrict__ Ain, float* __restrict__ out, int B) {
  __shared__ float Alds[NV * LDA];
  {
    const int t = threadIdx.x;
    if (t < 64) {
      const int row = t >> 2, seg = t & 3;
      float4 a = *reinterpret_cast<const float4*>(Ain + row * NV + seg * 4);
      *reinterpret_cast<float4*>(&Alds[row * LDA + seg * 4]) = a;
    }
  }
  __syncthreads();

  const int tid = blockIdx.x * blockDim.x + threadIdx.x;
  const int g = tid >> 2, l = tid & 3;
  if (g >= B) return;

  float y[4], x[4];
  {
    float4 t = *reinterpret_cast<const float4*>(y0 + g * NV + 4 * l);
    y[0] = t.x; y[1] = t.y; y[2] = t.z; y[3] = t.w;
    float4 u = *reinterpret_cast<const float4*>(xin + g * NV + 4 * l);
    x[0] = u.x; x[1] = u.y; x[2] = u.z; x[3] = u.w;
  }

  float eqf[4], neqf[4];
#pragma unroll
  for (int q = 0; q < 4; ++q) {
    eqf[q] = (l == q) ? 1.0f : 0.0f;
    neqf[q] = 1.0f - eqf[q];
  }

  const float* __restrict__ Arow0 = &Alds[(4 * l) * LDA];

#pragma unroll 1  // ~1k-instr body; full unroll would thrash I-cache
  for (int it = 0; it < MAX_ITER; ++it) {
    // 1) issue M loads first: LDS latency hides under trig below
    float M[4][16];
    static_for<4>([&](auto MM) {
      constexpr int m = MM.value;
      static_for<4>([&](auto TT) {
        constexpr int t = TT.value;
        float4 a4 = *reinterpret_cast<const float4*>(Arow0 + m * LDA + 4 * t);
        M[m][4 * t + 0] = a4.x; M[m][4 * t + 1] = a4.y;
        M[m][4 * t + 2] = a4.z; M[m][4 * t + 3] = a4.w;
      });
    });

    // 2) trig + diagonal term (hw v_sin/v_cos: args O(1) rad)
    float s4[4], rc[4], tdiag[4], y2[4];
#pragma unroll
    for (int m = 0; m < 4; ++m) {
      y2[m] = y[m] * y[m];
      s4[m] = __sinf(y[m]);
      float c = __cosf(y[m]);
      rc[m] = rcp_fast(c);
      tdiag[m] = 3.0f * y2[m] * rc[m];
    }
    float sf[16];
    static_for<16>([&](auto JJ) {
      constexpr int j = JJ.value;
      sf[j] = qbcast<(j >> 2)>(s4[j & 3]);
    });

    // 3) residual b = x - y^3 - A*sin(y) (uses M==A, BEFORE diag add)
    float b[4];
#pragma unroll
    for (int m = 0; m < 4; ++m) b[m] = x[m] - y2[m] * y[m];
    static_for<4>([&](auto MM) {
      constexpr int m = MM.value;
      static_for<16>([&](auto JJ) {
        constexpr int j = JJ.value;
        b[m] = __builtin_fmaf(-M[m][j], sf[j], b[m]);
      });
    });
    // diag add: row 4l+m's diagonal is col block t==l, slot m
    static_for<4>([&](auto MM) {
      constexpr int m = MM.value;
      static_for<4>([&](auto TT) {
        constexpr int t = TT.value;
        M[m][4 * t + m] = __builtin_fmaf(eqf[t], tdiag[m], M[m][4 * t + m]);
      });
    });

    // 4) pipelined unpivoted Gauss-Jordan (M diag-dominant by construction)
    float dginv[4] = {0.0f, 0.0f, 0.0f, 0.0f};
    // prologue: pivot 0
    float f[4], bk;
    {
      float invl = rcp_fast(M[0][0]);
      float inv = qbcast<0>(invl);
#pragma unroll
      for (int m = 0; m < 4; ++m) f[m] = M[m][0] * inv;
      f[0] *= neqf[0];
      dginv[0] = (l == 0) ? inv : dginv[0];
      bk = qbcast<0>(b[0]);
    }

    static_for<16>([&](auto KK) {
      constexpr int k = KK.value;
      constexpr int q = k >> 2, mk = k & 3;
      constexpr int k1 = k + 1;

      // finalize next pivot column first
      if constexpr (k1 <= 15) {
        float rkj = qbcast<q>(M[mk][k1]);
#pragma unroll
        for (int m = 0; m < 4; ++m) M[m][k1] = __builtin_fmaf(-f[m], rkj, M[m][k1]);
      }
      // start next pivot's rcp immediately (overlaps the work below)
      float invn = 0.0f;
      if constexpr (k1 <= 15) invn = rcp_fast(M[k1 & 3][k1]);

      // b elimination for step k (rcp shadow)
#pragma unroll
      for (int m = 0; m < 4; ++m) b[m] = __builtin_fmaf(-f[m], bk, b[m]);

      // col k+2 (more rcp shadow)
      if constexpr (k + 2 <= 15) {
        float rkj = qbcast<q>(M[mk][k + 2]);
#pragma unroll
        for (int m = 0; m < 4; ++m) M[m][k + 2] = __builtin_fmaf(-f[m], rkj, M[m][k + 2]);
      }

      // next step's f / bk, computed mid-burst
      float fn[4], bkn = 0.0f;
      if constexpr (k1 <= 15) {
        constexpr int q1 = k1 >> 2, mk1 = k1 & 3;
        float invb = qbcast<q1>(invn);
#pragma unroll
        for (int m = 0; m < 4; ++m) fn[m] = M[m][k1] * invb;
        fn[mk1] *= neqf[q1];
        dginv[mk1] = (l == q1) ? invb : dginv[mk1];
        bkn = qbcast<q1>(b[mk1]);
      }

      // sweep remaining columns k+3..15
      static_for<((k + 3 <= 15) ? (13 - k) : 0)>([&](auto JJ) {
        constexpr int j = k + 3 + JJ.value;
        float rkj = qbcast<q>(M[mk][j]);
#pragma unroll
        for (int m = 0; m < 4; ++m) M[m][j] = __builtin_fmaf(-f[m], rkj, M[m][j]);
      });

      if constexpr (k1 <= 15) {
#pragma unroll
        for (int m = 0; m < 4; ++m) f[m] = fn[m];
        bk = bkn;
      }
    });

    // 5) u = b*dginv ; delta = u/cos ; y += STEP*delta
#pragma unroll
    for (int m = 0; m < 4; ++m) {
      float u = b[m] * dginv[m];
      y[m] = __builtin_fmaf(STEP, u * rc[m], y[m]);
    }
  }

  float4 o;
  o.x = y[0]; o.y = y[1]; o.z = y[2]; o.w = y[3];
  *reinterpret_cast<float4*>(out + g * NV + 4 * l) = o;
}

extern "C" void kernel_launch(void* const* d_in, const int* in_sizes, int n_in,
                              void* d_out, int out_size, void* d_ws, size_t ws_size,
                              hipStream_t stream) {
  const float* y = (const float*)d_in[0];
  const float* x = (const float*)d_in[1];
  const float* A = (const float*)d_in[2];
  float* out = (float*)d_out;
  const int B = in_sizes[0] / NV;  // 32768
  const int threads = B * 4;       // one quad per system
  dim3 block(256);
  dim3 grid((threads + block.x - 1) / block.x);
  hipLaunchKernelGGL(newton16, grid, block, 0, stream, y, x, A, out, B);
}